// Round 1
// baseline (1017.473 us; speedup 1.0000x reference)
//
#include <hip/hip_runtime.h>

#define SP 262144                 // 64^3 spatial points
#define NELEM (64 * SP)           // per-batch elements for GN (16777216)
#define H1 128
#define H2C 256
#define C0 64

// workspace layout (bytes)
#define Y_OFF      0L                       // y256 bf16: 2*256*SP*2 = 268435456
#define G_OFF      268435456L               // g bf16:    2*128*SP*2 = 134217728
#define STATS_OFF  402653184L               // 4 floats: sum0, sq0, sum1, sq1
#define POOLED_OFF (STATS_OFF + 256)        // 256 floats
#define ATTN_OFF   (POOLED_OFF + 1024)      // 256 floats

typedef __attribute__((ext_vector_type(8))) short bf16x8;
typedef __attribute__((ext_vector_type(4))) float f32x4;

__device__ inline unsigned short f2bf(float f) {
    union { float f; unsigned u; } v; v.f = f;
    unsigned r = v.u + 0x7fffu + ((v.u >> 16) & 1u);
    return (unsigned short)(r >> 16);
}

// ---------------- K1: GroupNorm(1-group) stats: per-batch sum / sumsq ----------------
__global__ __launch_bounds__(256) void k_stats(const float* __restrict__ x,
                                               float* __restrict__ stats) {
    int b = blockIdx.x >> 10;                       // 1024 blocks per batch
    const float4* p = (const float4*)(x + (long)b * NELEM +
                                      (long)(blockIdx.x & 1023) * 16384);
    float s = 0.f, q = 0.f;
    for (int i = threadIdx.x; i < 4096; i += 256) {
        float4 v = p[i];
        s += (v.x + v.y) + (v.z + v.w);
        q += (v.x * v.x + v.y * v.y) + (v.z * v.z + v.w * v.w);
    }
#pragma unroll
    for (int m = 32; m; m >>= 1) { s += __shfl_xor(s, m); q += __shfl_xor(q, m); }
    __shared__ float red[8];
    int t = threadIdx.x;
    if ((t & 63) == 0) { red[(t >> 6) * 2] = s; red[(t >> 6) * 2 + 1] = q; }
    __syncthreads();
    if (t == 0) {
        atomicAdd(&stats[b * 2 + 0], red[0] + red[2] + red[4] + red[6]);
        atomicAdd(&stats[b * 2 + 1], red[1] + red[3] + red[5] + red[7]);
    }
}

// ---------------- K2: GN apply + pre 1x1 conv (64->256) via MFMA, bf16 out ----------------
// block: 512 thr (8 waves), 128 points; each wave computes 32 out-ch x 128 pts.
__global__ __launch_bounds__(512) void k_pre(const float* __restrict__ x,
                                             const float* __restrict__ gw,
                                             const float* __restrict__ gb,
                                             const float* __restrict__ pw,
                                             const float* __restrict__ pb,
                                             const float* __restrict__ stats,
                                             unsigned short* __restrict__ y) {
    __shared__ unsigned short xt[128 * 72];         // [p][c], 144B row stride (16B mult)
    int blk = blockIdx.x;                           // 4096 blocks
    int b = blk >> 11;
    long p0 = (long)(blk & 2047) * 128;
    const float n_inv = 1.f / 16777216.f;
    float mu = stats[b * 2] * n_inv;
    float ms = stats[b * 2 + 1] * n_inv;
    float rstd = rsqrtf(fmaxf(ms - mu * mu, 0.f) + 1e-5f);

    int t = threadIdx.x;
    int pl = t & 127, cg = t >> 7;                  // cg 0..3
    const float* xb = x + (long)b * NELEM + p0 + pl;
#pragma unroll
    for (int k = 0; k < 2; ++k) {
        int c0 = (k * 4 + cg) * 8;                  // covers c chunks 0..56 step 8
        union { unsigned short us[8]; bf16x8 v; } tmp;
#pragma unroll
        for (int j = 0; j < 8; ++j) {
            int c = c0 + j;
            float xv = xb[(long)c * SP];
            float xn = (xv - mu) * (rstd * gw[c]) + gb[c];
            tmp.us[j] = f2bf(xn);
        }
        *(bf16x8*)&xt[pl * 72 + c0] = tmp.v;
    }
    __syncthreads();

    int wv = t >> 6, l = t & 63, lr = l & 15, lg = l >> 4;
    // A fragments: W rows o = wv*32 + mt*16 + lr, k = ks*32 + lg*8
    bf16x8 wa[2][2];
#pragma unroll
    for (int mt = 0; mt < 2; ++mt)
#pragma unroll
        for (int ks = 0; ks < 2; ++ks) {
            const float* wp = pw + (wv * 32 + mt * 16 + lr) * 64 + ks * 32 + lg * 8;
            union { unsigned short us[8]; bf16x8 v; } a;
#pragma unroll
            for (int j = 0; j < 8; ++j) a.us[j] = f2bf(wp[j]);
            wa[mt][ks] = a.v;
        }
    f32x4 acc[2][8];
#pragma unroll
    for (int mt = 0; mt < 2; ++mt)
#pragma unroll
        for (int nt = 0; nt < 8; ++nt) acc[mt][nt] = (f32x4){0.f, 0.f, 0.f, 0.f};

#pragma unroll
    for (int nt = 0; nt < 8; ++nt) {
        bf16x8 b0 = *(const bf16x8*)&xt[(nt * 16 + lr) * 72 + lg * 8];
        bf16x8 b1 = *(const bf16x8*)&xt[(nt * 16 + lr) * 72 + 32 + lg * 8];
#pragma unroll
        for (int mt = 0; mt < 2; ++mt) {
            acc[mt][nt] = __builtin_amdgcn_mfma_f32_16x16x32_bf16(wa[mt][0], b0, acc[mt][nt], 0, 0, 0);
            acc[mt][nt] = __builtin_amdgcn_mfma_f32_16x16x32_bf16(wa[mt][1], b1, acc[mt][nt], 0, 0, 0);
        }
    }
    // epilogue: +pre_b, cast bf16, store. D: row=lg*4+i, col=lr.
#pragma unroll
    for (int mt = 0; mt < 2; ++mt) {
        int ob = wv * 32 + mt * 16 + lg * 4;
#pragma unroll
        for (int i = 0; i < 4; ++i) {
            float bias = pb[ob + i];
            unsigned short* yo = y + (long)(b * H2C + ob + i) * SP + p0;
#pragma unroll
            for (int nt = 0; nt < 8; ++nt)
                yo[nt * 16 + lr] = f2bf(acc[mt][nt][i] + bias);
        }
    }
}

// ---------------- K3: depthwise dilated 3x3x3 conv + GLU + pooled sum ----------------
// grid: b(2) x chpair(128) x tiles(8d x 8h, full w). block 256 thr.
__global__ __launch_bounds__(256) void k_conv(const unsigned short* __restrict__ y,
                                              const float* __restrict__ cw,
                                              const float* __restrict__ cb,
                                              unsigned short* __restrict__ g,
                                              float* __restrict__ pooled) {
    __shared__ unsigned short lds[2][14 * 16 * 72]; // [dz][hz(pad16)][wz], 144B rows
    __shared__ float wc[54];
    __shared__ float red[4];
    int blk = blockIdx.x;
    int tile = blk & 63, bo = blk >> 6;
    int o = bo & 127, b = bo >> 7;
    int d0 = (tile >> 3) * 8, h0 = (tile & 7) * 8;
    int t = threadIdx.x;
    if (t < 54) {
        int cc = t / 27, k = t - cc * 27;
        wc[t] = cw[(o + cc * 128) * 27 + k];
    }
#pragma unroll
    for (int cc = 0; cc < 2; ++cc) {
        const unsigned short* src = y + (long)(b * H2C + o + cc * 128) * SP;
        int wq = t & 15;
        // interior: wz 4..67 <-> w 0..63 (w-halo is always OOB -> constant zero)
#pragma unroll
        for (int i = 0; i < 14; ++i) {
            int r = (t >> 4) + (i << 4);            // 224 row slots
            int dz = r >> 4, hz = r & 15;
            int d = d0 + dz - 3, h = h0 + hz - 3;
            uint2 v = {0u, 0u};
            if (hz < 14 && (unsigned)d < 64u && (unsigned)h < 64u)
                v = *(const uint2*)(src + ((long)d << 12) + (h << 6) + (wq << 2));
            *(uint2*)&lds[cc][(dz * 16 + hz) * 72 + 4 + (wq << 2)] = v;
        }
        // zero edge slots wz {0..3, 68..71}
#pragma unroll
        for (int i = 0; i < 7; ++i) {
            int e = t + (i << 8);
            int r = e >> 3, k = e & 7;
            int wz = k + ((k >= 4) ? 64 : 0);
            lds[cc][r * 72 + wz] = 0;
        }
    }
    __syncthreads();

    int wq = t & 3, hh = (t >> 2) & 7, dd = t >> 5;
    int w0 = wq << 4;                               // 16 outputs along w per thread
    float za[16], zcur[16];
#pragma unroll
    for (int cc = 0; cc < 2; ++cc) {
        float bias = cb[o + cc * 128];
#pragma unroll
        for (int j = 0; j < 16; ++j) zcur[j] = bias;
#pragma unroll
        for (int kd = 0; kd < 3; ++kd) {
#pragma unroll
            for (int kh = 0; kh < 3; ++kh) {
                const unsigned short* row = &lds[cc][((dd + kd * 3) * 16 + (hh + kh * 3)) * 72];
                uint4 q0 = *(const uint4*)&row[w0];
                uint4 q1 = *(const uint4*)&row[w0 + 8];
                uint4 q2 = *(const uint4*)&row[w0 + 16];
                unsigned dws[12] = {q0.x, q0.y, q0.z, q0.w, q1.x, q1.y, q1.z, q1.w,
                                    q2.x, q2.y, q2.z, q2.w};
                float v[24];
#pragma unroll
                for (int m = 0; m < 12; ++m) {
                    union { unsigned u; float f; } lo, hi;
                    lo.u = dws[m] << 16;
                    hi.u = dws[m] & 0xffff0000u;
                    v[2 * m] = lo.f; v[2 * m + 1] = hi.f;
                }
                int wb = cc * 27 + kd * 9 + kh * 3;
                float w_0 = wc[wb + 0], w_1 = wc[wb + 1], w_2 = wc[wb + 2];
#pragma unroll
                for (int j = 0; j < 16; ++j)
                    zcur[j] += w_0 * v[j + 1] + w_1 * v[j + 4] + w_2 * v[j + 7];
            }
        }
        if (cc == 0) {
#pragma unroll
            for (int j = 0; j < 16; ++j) za[j] = zcur[j];
        }
    }
    float psum = 0.f;
    union { unsigned short us[16]; uint4 q[2]; } pk;
#pragma unroll
    for (int j = 0; j < 16; ++j) {
        float gvj = za[j] * zcur[j];
        psum += gvj;
        pk.us[j] = f2bf(gvj);
    }
    unsigned short* gp = g + (long)(b * H1 + o) * SP + ((long)(d0 + dd) << 12) +
                         ((h0 + hh) << 6) + w0;
    *(uint4*)gp = pk.q[0];
    *(uint4*)(gp + 8) = pk.q[1];
#pragma unroll
    for (int m = 32; m; m >>= 1) psum += __shfl_xor(psum, m);
    if ((t & 63) == 0) red[t >> 6] = psum;
    __syncthreads();
    if (t == 0) atomicAdd(&pooled[b * H1 + o], red[0] + red[1] + red[2] + red[3]);
}

// ---------------- K4: attn = (pooled/SP) @ sca_w.T + sca_b  (1 block) ----------------
__global__ __launch_bounds__(256) void k_attn(const float* __restrict__ pooled,
                                              const float* __restrict__ sw,
                                              const float* __restrict__ sb,
                                              float* __restrict__ attn) {
    int t = threadIdx.x;
    int b = t >> 7, o = t & 127;
    const float inv = 1.f / (float)SP;
    float s = sb[o];
    for (int h = 0; h < 128; ++h)
        s += pooled[b * H1 + h] * inv * sw[o * H1 + h];
    attn[t] = s;
}

// ---------------- K5: x*attn -> post 1x1 conv (128->64) via MFMA + bias + residual ----------------
// block: 256 thr (4 waves), 128 points; wave computes 16 out-ch x 128 pts, K=128.
__global__ __launch_bounds__(256) void k_post(const unsigned short* __restrict__ g,
                                              const float* __restrict__ x,
                                              const float* __restrict__ pw2,
                                              const float* __restrict__ pb2,
                                              const float* __restrict__ attn,
                                              float* __restrict__ out) {
    __shared__ unsigned short gt[128 * 136];        // [p][h], 272B row stride
    int blk = blockIdx.x;                           // 4096 blocks
    int b = blk >> 11;
    long p0 = (long)(blk & 2047) * 128;
    int t = threadIdx.x;
    int pl = t & 127, hg = t >> 7;                  // hg 0/1
    const unsigned short* gb_ = g + (long)b * H1 * SP + p0 + pl;
#pragma unroll
    for (int i = 0; i < 8; ++i) {
        int hb = (i * 2 + hg) * 8;
        union { unsigned short us[8]; bf16x8 v; } tmp;
#pragma unroll
        for (int j = 0; j < 8; ++j) tmp.us[j] = gb_[(long)(hb + j) * SP];
        *(bf16x8*)&gt[pl * 136 + hb] = tmp.v;
    }
    __syncthreads();

    int wv = t >> 6, l = t & 63, lr = l & 15, lg = l >> 4;
    const float* ab = attn + b * H1;
    bf16x8 wa[4];
#pragma unroll
    for (int ks = 0; ks < 4; ++ks) {
        int c = wv * 16 + lr;
        int h0 = ks * 32 + lg * 8;
        const float* wp = pw2 + c * H1 + h0;
        union { unsigned short us[8]; bf16x8 v; } a;
#pragma unroll
        for (int j = 0; j < 8; ++j) a.us[j] = f2bf(wp[j] * ab[h0 + j]);
        wa[ks] = a.v;
    }
    f32x4 acc[8];
#pragma unroll
    for (int nt = 0; nt < 8; ++nt) acc[nt] = (f32x4){0.f, 0.f, 0.f, 0.f};
#pragma unroll
    for (int nt = 0; nt < 8; ++nt) {
#pragma unroll
        for (int ks = 0; ks < 4; ++ks) {
            bf16x8 bv = *(const bf16x8*)&gt[(nt * 16 + lr) * 136 + ks * 32 + lg * 8];
            acc[nt] = __builtin_amdgcn_mfma_f32_16x16x32_bf16(wa[ks], bv, acc[nt], 0, 0, 0);
        }
    }
#pragma unroll
    for (int i = 0; i < 4; ++i) {
        int c = wv * 16 + lg * 4 + i;
        float bias = pb2[c];
        const float* xr = x + (long)(b * C0 + c) * SP + p0;
        float* orow = out + (long)(b * C0 + c) * SP + p0;
#pragma unroll
        for (int nt = 0; nt < 8; ++nt) {
            int pp = nt * 16 + lr;
            orow[pp] = acc[nt][i] + bias + xr[pp];
        }
    }
}

extern "C" void kernel_launch(void* const* d_in, const int* in_sizes, int n_in,
                              void* d_out, int out_size, void* d_ws, size_t ws_size,
                              hipStream_t stream) {
    const float* x   = (const float*)d_in[0];
    const float* gnw = (const float*)d_in[1];
    const float* gnb = (const float*)d_in[2];
    const float* pw  = (const float*)d_in[3];
    const float* pb  = (const float*)d_in[4];
    const float* cw  = (const float*)d_in[5];
    const float* cb  = (const float*)d_in[6];
    const float* sw  = (const float*)d_in[7];
    const float* sb  = (const float*)d_in[8];
    const float* pw2 = (const float*)d_in[9];
    const float* pb2 = (const float*)d_in[10];
    float* out = (float*)d_out;
    char* ws = (char*)d_ws;

    unsigned short* y256 = (unsigned short*)(ws + Y_OFF);
    unsigned short* gbuf = (unsigned short*)(ws + G_OFF);
    float* stats  = (float*)(ws + STATS_OFF);
    float* pooled = (float*)(ws + POOLED_OFF);
    float* attn   = (float*)(ws + ATTN_OFF);

    hipMemsetAsync(ws + STATS_OFF, 0, 2048, stream);
    hipLaunchKernelGGL(k_stats, dim3(2048), dim3(256), 0, stream, x, stats);
    hipLaunchKernelGGL(k_pre,   dim3(4096), dim3(512), 0, stream, x, gnw, gnb, pw, pb, stats, y256);
    hipLaunchKernelGGL(k_conv,  dim3(16384), dim3(256), 0, stream, y256, cw, cb, gbuf, pooled);
    hipLaunchKernelGGL(k_attn,  dim3(1),    dim3(256), 0, stream, pooled, sw, sb, attn);
    hipLaunchKernelGGL(k_post,  dim3(4096), dim3(256), 0, stream, gbuf, x, pw2, pb2, attn, out);
}